// Round 5
// baseline (20.697 us; speedup 1.0000x reference)
//
#include <hip/hip_runtime.h>
#include <math.h>

// ============================================================================
// Algebra (verified R2-R4): out_w = h01^T B_w h23, where
//   h01 = r0 (x) r1, h23 = r2 (x) r3, r_q = (c^2, c*s, s^2) of the encoder
//   RY half-angle; B_w is the 9x9 binned form of A_w = Re(U^dag Z_w U) and
//   U = the fixed 2-layer ansatz (params batch-uniform).
// Fused version: every block recomputes B_w in LDS (cheap, ~0.5us), removing
// the second kernel launch and the inter-kernel dependency from the graph.
// ============================================================================

// ---- shuffle-parallel basis-column simulation (phase 1) --------------------
// Lane l of wave w holds amplitude m = l&15 of basis column j = 4w + (l>>4).
// Gate masks 1/2/4/8 keep __shfl_xor within each 16-lane group.

template<int W>
__device__ __forceinline__ void ry_sh(float& x, float& y, float c, float s, int m) {
    constexpr int M = 1 << (3 - W);
    float px = __shfl_xor(x, M, 64);
    float py = __shfl_xor(y, M, 64);
    float sg = (m & M) ? s : -s;
    x = fmaf(sg, px, c * x);
    y = fmaf(sg, py, c * y);
}

template<int W>
__device__ __forceinline__ void rz_sh(float& x, float& y, float c, float s, int m) {
    constexpr int M = 1 << (3 - W);
    float sg = (m & M) ? -s : s;   // bit0: *(c - i s); bit1: *(c + i s)
    float nx = fmaf(sg, y, c * x);
    float ny = fmaf(-sg, x, c * y);
    x = nx; y = ny;
}

template<int C, int T>
__device__ __forceinline__ void cnot_sh(float& x, float& y, int m) {
    constexpr int MC = 1 << (3 - C), MT = 1 << (3 - T);
    float px = __shfl_xor(x, MT, 64);
    float py = __shfl_xor(y, MT, 64);
    bool ctl = (m & MC) != 0;
    x = ctl ? px : x;
    y = ctl ? py : y;
}

template<int A, int Bq>
__device__ __forceinline__ void ansatz_sh(float& x, float& y,
                                          const float* pc, const float* ps, int m) {
    ry_sh<A >(x, y, pc[0], ps[0], m);
    rz_sh<A >(x, y, pc[1], ps[1], m);
    ry_sh<Bq>(x, y, pc[2], ps[2], m);
    rz_sh<Bq>(x, y, pc[3], ps[3], m);
    cnot_sh<A, Bq>(x, y, m);
    ry_sh<A >(x, y, pc[4], ps[4], m);
    rz_sh<A >(x, y, pc[5], ps[5], m);
    ry_sh<Bq>(x, y, pc[6], ps[6], m);
}

// ---- fused kernel ----------------------------------------------------------

__global__ __launch_bounds__(256) void qfused_kernel(
        const float* __restrict__ patches,
        const float* __restrict__ params,
        float* __restrict__ out, int B, int stride /* total threads */) {
    __shared__ float2 U[16][17];   // [m][j], padded
    __shared__ float Bs[324];

    int tid = threadIdx.x;
    for (int t = tid; t < 324; t += 256) Bs[t] = 0.f;

    // phase 1: simulate 16 basis columns across the block's 4 waves
    {
        float pc[2][7], ps[2][7];
        #pragma unroll
        for (int l = 0; l < 2; ++l)
            #pragma unroll
            for (int k = 0; k < 7; ++k)
                __sincosf(0.5f * params[l * 7 + k], &ps[l][k], &pc[l][k]);

        int m = tid & 15;
        int j = tid >> 4;
        float x = (m == j) ? 1.f : 0.f;
        float y = 0.f;

        #pragma unroll
        for (int l = 0; l < 2; ++l) {
            ansatz_sh<0, 1>(x, y, pc[l], ps[l], m);
            ansatz_sh<1, 2>(x, y, pc[l], ps[l], m);
            ansatz_sh<2, 3>(x, y, pc[l], ps[l], m);
            ansatz_sh<3, 0>(x, y, pc[l], ps[l], m);
        }
        U[m][j] = make_float2(x, y);
    }
    __syncthreads();

    // phase 2: thread (j,k) computes a(j,k,m) once, bins all 4 wires
    {
        int j = tid >> 4, k = tid & 15;
        float a0 = 0.f, a1 = 0.f, a2 = 0.f, a3 = 0.f;
        #pragma unroll
        for (int m = 0; m < 16; ++m) {
            float2 uj = U[m][j], uk = U[m][k];
            float a = uj.x * uk.x + uj.y * uk.y;
            a0 += (m & 8) ? -a : a;
            a1 += (m & 4) ? -a : a;
            a2 += (m & 2) ? -a : a;
            a3 += (m & 1) ? -a : a;
        }
        int m0 = ((j >> 3) & 1) + ((k >> 3) & 1);
        int m1 = ((j >> 2) & 1) + ((k >> 2) & 1);
        int m2 = ((j >> 1) & 1) + ((k >> 1) & 1);
        int m3 = ((j >> 0) & 1) + ((k >> 0) & 1);
        int base = (m0 * 3 + m1) * 9 + (m2 * 3 + m3);
        atomicAdd(&Bs[  0 + base], a0);
        atomicAdd(&Bs[ 81 + base], a1);
        atomicAdd(&Bs[162 + base], a2);
        atomicAdd(&Bs[243 + base], a3);
    }
    __syncthreads();

    // phase 3: per-element bilinear evaluation (grid-stride, 2 elems/thread)
    for (int i = blockIdx.x * blockDim.x + tid; i < B; i += stride) {
        float4 x4 = reinterpret_cast<const float4*>(patches)[i];
        float xs[4] = {x4.x, x4.y, x4.z, x4.w};

        float r[4][3];
        #pragma unroll
        for (int w = 0; w < 4; ++w) {
            float sig = 1.0f / (1.0f + __expf(-xs[w]));
            float half = sig * (0.5f * (float)M_PI);
            float s, c;
            __sincosf(half, &s, &c);
            r[w][0] = c * c;
            r[w][1] = c * s;
            r[w][2] = s * s;
        }

        float h01[9], h23[9];
        #pragma unroll
        for (int a = 0; a < 3; ++a) {
            #pragma unroll
            for (int b = 0; b < 3; ++b) {
                h01[a * 3 + b] = r[0][a] * r[1][b];
                h23[a * 3 + b] = r[2][a] * r[3][b];
            }
        }

        float o[4];
        #pragma unroll
        for (int w = 0; w < 4; ++w) {
            float acc = 0.f;
            #pragma unroll
            for (int j = 0; j < 9; ++j) {
                float t = 0.f;
                #pragma unroll
                for (int k = 0; k < 9; ++k)
                    t = fmaf(Bs[w * 81 + j * 9 + k], h23[k], t);
                acc = fmaf(h01[j], t, acc);
            }
            o[w] = acc;
        }

        reinterpret_cast<float4*>(out)[i] = make_float4(o[0], o[1], o[2], o[3]);
    }
}

extern "C" void kernel_launch(void* const* d_in, const int* in_sizes, int n_in,
                              void* d_out, int out_size, void* d_ws, size_t ws_size,
                              hipStream_t stream) {
    const float* patches = (const float*)d_in[0];
    const float* params  = (const float*)d_in[1];
    float* out = (float*)d_out;

    int B = in_sizes[0] / 4;
    int block = 256;
    int grid = 512;                      // 2 elements per thread at B=262144
    int stride = grid * block;
    if (stride > B) {                    // small-B fallback
        grid = (B + block - 1) / block;
        stride = grid * block;
    }
    qfused_kernel<<<grid, block, 0, stream>>>(patches, params, out, B, stride);
}

// Round 6
// 14.434 us; speedup vs baseline: 1.4338x; 1.4338x over previous
//
#include <hip/hip_runtime.h>
#include <math.h>

// ============================================================================
// Algebra (verified R2-R5): out_w = h01^T B_w h23, where
//   h01 = r0 (x) r1, h23 = r2 (x) r3, r_q = ((1+cos t)/2, sin t/2, (1-cos t)/2)
//   with t = pi*sigmoid(x_q); B_w is the 9x9 binned form of
//   A_w = Re(U^dag Z_w U), U = fixed 2-layer ansatz (params batch-uniform).
// Two-kernel structure (R4, proven): fused per-block setup regressed (R5) --
// low TLP + LDS broadcast reads; replay overhead is ~13us regardless of node
// count, so the extra launch is free.
// B layout: wire-interleaved Bmat[(j*9+k)*4 + w] so qmain reads one uniform
// s_load_dwordx4 per (j,k) and packs wire-pairs into v_pk_fma_f32.
// ============================================================================

// ---- shuffle-parallel basis-column simulation ------------------------------
// Lane l of wave w holds amplitude m = l&15 of basis column j = 4w + (l>>4).

template<int W>
__device__ __forceinline__ void ry_sh(float& x, float& y, float c, float s, int m) {
    constexpr int M = 1 << (3 - W);
    float px = __shfl_xor(x, M, 64);
    float py = __shfl_xor(y, M, 64);
    float sg = (m & M) ? s : -s;
    x = fmaf(sg, px, c * x);
    y = fmaf(sg, py, c * y);
}

template<int W>
__device__ __forceinline__ void rz_sh(float& x, float& y, float c, float s, int m) {
    constexpr int M = 1 << (3 - W);
    float sg = (m & M) ? -s : s;
    float nx = fmaf(sg, y, c * x);
    float ny = fmaf(-sg, x, c * y);
    x = nx; y = ny;
}

template<int C, int T>
__device__ __forceinline__ void cnot_sh(float& x, float& y, int m) {
    constexpr int MC = 1 << (3 - C), MT = 1 << (3 - T);
    float px = __shfl_xor(x, MT, 64);
    float py = __shfl_xor(y, MT, 64);
    bool ctl = (m & MC) != 0;
    x = ctl ? px : x;
    y = ctl ? py : y;
}

template<int A, int Bq>
__device__ __forceinline__ void ansatz_sh(float& x, float& y,
                                          const float* pc, const float* ps, int m) {
    ry_sh<A >(x, y, pc[0], ps[0], m);
    rz_sh<A >(x, y, pc[1], ps[1], m);
    ry_sh<Bq>(x, y, pc[2], ps[2], m);
    rz_sh<Bq>(x, y, pc[3], ps[3], m);
    cnot_sh<A, Bq>(x, y, m);
    ry_sh<A >(x, y, pc[4], ps[4], m);
    rz_sh<A >(x, y, pc[5], ps[5], m);
    ry_sh<Bq>(x, y, pc[6], ps[6], m);
}

__global__ __launch_bounds__(256) void qsetup_kernel(
        const float* __restrict__ params,
        float* __restrict__ Bmat /* [81][4] wire-interleaved */) {
    __shared__ float2 U[16][17];   // [m][j], padded
    __shared__ float Bs[324];

    int tid = threadIdx.x;
    for (int t = tid; t < 324; t += 256) Bs[t] = 0.f;

    // phase 1: simulate 16 basis columns across 4 waves
    {
        float pc[2][7], ps[2][7];
        #pragma unroll
        for (int l = 0; l < 2; ++l)
            #pragma unroll
            for (int k = 0; k < 7; ++k)
                __sincosf(0.5f * params[l * 7 + k], &ps[l][k], &pc[l][k]);

        int m = tid & 15;
        int j = tid >> 4;
        float x = (m == j) ? 1.f : 0.f;
        float y = 0.f;

        #pragma unroll
        for (int l = 0; l < 2; ++l) {
            ansatz_sh<0, 1>(x, y, pc[l], ps[l], m);
            ansatz_sh<1, 2>(x, y, pc[l], ps[l], m);
            ansatz_sh<2, 3>(x, y, pc[l], ps[l], m);
            ansatz_sh<3, 0>(x, y, pc[l], ps[l], m);
        }
        U[m][j] = make_float2(x, y);
    }
    __syncthreads();

    // phase 2: thread (j,k) computes a(j,k,m) once, bins all 4 wires
    {
        int j = tid >> 4, k = tid & 15;
        float a0 = 0.f, a1 = 0.f, a2 = 0.f, a3 = 0.f;
        #pragma unroll
        for (int m = 0; m < 16; ++m) {
            float2 uj = U[m][j], uk = U[m][k];
            float a = uj.x * uk.x + uj.y * uk.y;
            a0 += (m & 8) ? -a : a;
            a1 += (m & 4) ? -a : a;
            a2 += (m & 2) ? -a : a;
            a3 += (m & 1) ? -a : a;
        }
        int m0 = ((j >> 3) & 1) + ((k >> 3) & 1);
        int m1 = ((j >> 2) & 1) + ((k >> 2) & 1);
        int m2 = ((j >> 1) & 1) + ((k >> 1) & 1);
        int m3 = ((j >> 0) & 1) + ((k >> 0) & 1);
        int base = ((m0 * 3 + m1) * 9 + (m2 * 3 + m3)) * 4;
        atomicAdd(&Bs[base + 0], a0);
        atomicAdd(&Bs[base + 1], a1);
        atomicAdd(&Bs[base + 2], a2);
        atomicAdd(&Bs[base + 3], a3);
    }
    __syncthreads();

    for (int t = tid; t < 324; t += 256) Bmat[t] = Bs[t];
}

// ---- main: per-element bilinear, wire-pairs packed for v_pk_fma_f32 --------

__global__ __launch_bounds__(256) void qmain_kernel(
        const float* __restrict__ patches,
        const float* __restrict__ Bmat,
        float* __restrict__ out, int B) {
    int i = blockIdx.x * blockDim.x + threadIdx.x;
    if (i >= B) return;

    float4 x4 = reinterpret_cast<const float4*>(patches)[i];
    float xs[4] = {x4.x, x4.y, x4.z, x4.w};

    // r_q via full-angle: t = pi*sigmoid(x); c2=(1+cos t)/2, cs=sin t/2, s2=(1-cos t)/2
    float r[4][3];
    #pragma unroll
    for (int w = 0; w < 4; ++w) {
        float sig = 1.0f / (1.0f + __expf(-xs[w]));
        float th = sig * (float)M_PI;
        float s, c;
        __sincosf(th, &s, &c);
        r[w][0] = 0.5f + 0.5f * c;
        r[w][1] = 0.5f * s;
        r[w][2] = 0.5f - 0.5f * c;
    }

    float h01[9], h23[9];
    #pragma unroll
    for (int a = 0; a < 3; ++a) {
        #pragma unroll
        for (int b = 0; b < 3; ++b) {
            h01[a * 3 + b] = r[0][a] * r[1][b];
            h23[a * 3 + b] = r[2][a] * r[3][b];
        }
    }

    const float4* Bv = reinterpret_cast<const float4*>(Bmat);  // Bv[j*9+k] = {B0,B1,B2,B3}
    float2 acc01 = make_float2(0.f, 0.f);
    float2 acc23 = make_float2(0.f, 0.f);
    #pragma unroll
    for (int j = 0; j < 9; ++j) {
        float2 t01 = make_float2(0.f, 0.f);
        float2 t23 = make_float2(0.f, 0.f);
        #pragma unroll
        for (int k = 0; k < 9; ++k) {
            float4 b = Bv[j * 9 + k];   // uniform -> s_load_dwordx4
            float hk = h23[k];
            t01.x = fmaf(b.x, hk, t01.x);
            t01.y = fmaf(b.y, hk, t01.y);
            t23.x = fmaf(b.z, hk, t23.x);
            t23.y = fmaf(b.w, hk, t23.y);
        }
        float hj = h01[j];
        acc01.x = fmaf(hj, t01.x, acc01.x);
        acc01.y = fmaf(hj, t01.y, acc01.y);
        acc23.x = fmaf(hj, t23.x, acc23.x);
        acc23.y = fmaf(hj, t23.y, acc23.y);
    }

    reinterpret_cast<float4*>(out)[i] =
        make_float4(acc01.x, acc01.y, acc23.x, acc23.y);
}

extern "C" void kernel_launch(void* const* d_in, const int* in_sizes, int n_in,
                              void* d_out, int out_size, void* d_ws, size_t ws_size,
                              hipStream_t stream) {
    const float* patches = (const float*)d_in[0];
    const float* params  = (const float*)d_in[1];
    float* out  = (float*)d_out;
    float* Bmat = (float*)d_ws;  // 324 floats = 1296 B of scratch

    qsetup_kernel<<<1, 256, 0, stream>>>(params, Bmat);

    int B = in_sizes[0] / 4;
    int block = 256;
    int grid = (B + block - 1) / block;
    qmain_kernel<<<grid, block, 0, stream>>>(patches, Bmat, out, B);
}